// Round 11
// baseline (400.393 us; speedup 1.0000x reference)
//
#include <hip/hip_runtime.h>
#include <math.h>

#define C_   128
#define HU_  128
#define WU_  192
#define HD_  64
#define WD_  96
#define HWD_ (HD_ * WD_)
#define NDP  (2 * HD_ * WD_)     // 12288 distinct down-pixels

typedef unsigned short u16;
typedef __attribute__((ext_vector_type(8))) short s8v;   // 8 bf16 = 4 VGPRs
typedef __attribute__((ext_vector_type(4))) float f4v;   // MFMA C/D

// ---- workspace layout (u16 units) ----
#define OFF_Q   0        // 2 layers x 16384
#define OFF_K   32768    // Wk' = diag(g)Wk (affine-folded)
#define OFF_V   65536    // Wv' = diag(g)Wv
#define OFF_O   98304
#define OFF_F1  131072   // 2 layers x 65536
#define OFF_F2  262144
#define OFF_XC  393216   // 49152 (out1 Wa+Wc, 128x384)
#define OFF_CC  442368   // 49152 (out1 Wb-Wc, 128x384)
#define OFF_NRM 491520   // normalized ctx bf16: (B,HD,WD,C) = 1572864 u16
#define OFF_VB  2064384  // folded v-bias: b@Wv + vb, 2x128 f32 = 512 u16
// ---- precompute extension (bisect: kv_kernel runs under guard; outputs
// consumed by NOBODY this round — isolates kv side-effects) ----
#define OFF_KB  2097152  // K: [2][NDP][128] bf16 = 3145728 u16
#define OFF_VT  5242880  // V^T: [2][128][NDP] bf16 = 3145728 u16
#define WS_NEED ((size_t)8388608 * 2)   // bytes

#define SLOT 2176        // u16 per LDS tile slot (16 rows x 136)

__device__ __forceinline__ u16 f2bf(float f) {
    unsigned u = __float_as_uint(f);
    unsigned r = (u + 0x7FFFu + ((u >> 16) & 1u)) >> 16;   // RNE
    return (u16)r;
}
__device__ __forceinline__ float bfu(u16 h) { return __uint_as_float(((unsigned)h) << 16); }

// paired f32->bf16 via HW packed convert (RNE, bit-identical to f2bf)
__device__ __forceinline__ void st2bf(u16* p0, u16* p1, float a, float b) {
    unsigned r;
    asm("v_cvt_pk_bf16_f32 %0, %1, %2" : "=v"(r) : "v"(a), "v"(b));
    *p0 = (u16)r;
    *p1 = (u16)(r >> 16);
}

__device__ __forceinline__ float gelu_tanh(float x) {
    float u = 1.5957691216057308f * (x + 0.044715f * x * x * x);
    float e = __expf(u);
    float th = 1.0f - 2.0f / (1.0f + e);
    return 0.5f * x * (1.0f + th);
}
__device__ __forceinline__ float fast_erf(float x) {
    float z = fabsf(x);
    float t = 1.0f / (1.0f + 0.3275911f * z);
    float p = t * (0.254829592f + t * (-0.284496736f + t * (1.421413741f +
              t * (-1.453152027f + t * 1.061405429f))));
    float r = 1.0f - p * __expf(-z * z);
    return copysignf(r, x);
}
__device__ __forceinline__ float gelu_erf(float x) {
    return 0.5f * x * (1.0f + fast_erf(x * 0.7071067811865476f));
}

// async global->LDS: each lane stages 16B; LDS dest = base + lane*16 (HW rule)
__device__ __forceinline__ void glds1(const u16* src, u16* dst, int lane) {
    __builtin_amdgcn_global_load_lds(
        (const __attribute__((address_space(1))) void*)(src + (size_t)lane * 8),
        (__attribute__((address_space(3))) void*)dst, 16, 0, 0);
}
// group protocol (4 waves share wlds; each wave stages 2 of a group's 8 chunks)
#define GW2() do { asm volatile("s_waitcnt vmcnt(2)" ::: "memory"); __builtin_amdgcn_s_barrier(); } while (0)
#define GW0() do { asm volatile("s_waitcnt vmcnt(0)" ::: "memory"); __builtin_amdgcn_s_barrier(); } while (0)
#define BAR() __builtin_amdgcn_s_barrier()
#define WFENCE() asm volatile("s_waitcnt lgkmcnt(0)" ::: "memory")

// ---------------- merged prologue: weight swizzles + affine fold + ctx LN ----------------
__global__ __launch_bounds__(256) void prologue_all(
    const float* __restrict__ q_w, const float* __restrict__ k_w,
    const float* __restrict__ v_w, const float* __restrict__ o_w,
    const float* __restrict__ f1w, const float* __restrict__ f2w,
    const float* __restrict__ o1w,
    const float* __restrict__ ctx_g, const float* __restrict__ ctx_b,
    const float* __restrict__ vb_in, const float* __restrict__ fm,
    u16* __restrict__ ws)
{
    if (blockIdx.x >= 242) {
        // ---- ctx LN path ----
        int row = blockIdx.x - 242;    // b*HD + y
        int b = row >> 6, y = row & 63;
        __shared__ float tile[128 * 97];
        __shared__ float smean[96], srst[96];
        u16* dst = ws + OFF_NRM;
        for (int idx = threadIdx.x; idx < 128 * 96; idx += 256) {
            int c = idx / 96, w = idx - c * 96;
            tile[c * 97 + w] = fm[(((size_t)b * 128 + c) * 64 + y) * 96 + w];
        }
        __syncthreads();
        if (threadIdx.x < 96) {
            int w = threadIdx.x;
            float s = 0.f, ss = 0.f;
            for (int c = 0; c < 128; ++c) { float v = tile[c * 97 + w]; s += v; ss += v * v; }
            float mn = s * (1.f / 128.f);
            smean[w] = mn;
            srst[w]  = rsqrtf(ss * (1.f / 128.f) - mn * mn + 1e-5f);
        }
        __syncthreads();
        for (int idx = threadIdx.x; idx < 96 * 16; idx += 256) {
            int w = idx >> 4, cg = idx & 15;
            float mn = smean[w], iv = srst[w];
            s8v o;
#pragma unroll
            for (int j = 0; j < 8; ++j)
                o[j] = (short)f2bf((tile[(8 * cg + j) * 97 + w] - mn) * iv);
            *(s8v*)(dst + ((size_t)row * 96 + w) * 128 + 8 * cg) = o;
        }
        return;
    }

    // ---- weight swizzle path ----
    int tid = blockIdx.x * 256 + threadIdx.x;
    int f = tid >> 6, lane = tid & 63;
    if (f >= 964) return;
    if (f >= 960) {                 // folded v-bias: vb' = b@Wv + vb
        int lf = f - 960;           // 0..3
        int ly = lf >> 1, col = (lf & 1) * 64 + lane;
        float s = vb_in[ly * 128 + col];
        const float* bp = ctx_b + ly * 128;
        const float* wp = v_w + (size_t)ly * 128 * 128 + col;
#pragma unroll 8
        for (int c = 0; c < 128; ++c) s += bp[c] * wp[(size_t)c * 128];
        ((float*)(ws + OFF_VB))[ly * 128 + col] = s;
        return;
    }
    int rq = 8 * (lane >> 4), cq = lane & 15;
    const float* src; const float* src2 = nullptr; float sgn = 1.f;
    int NT, N, dstoff, lf;
    bool scale_g = false;
    if (f < 64)       { src = q_w;  NT = 8;  N = 128; dstoff = OFF_Q;  lf = f; }
    else if (f < 128) { src = k_w;  NT = 8;  N = 128; dstoff = OFF_K;  lf = f - 64;  scale_g = true; }
    else if (f < 192) { src = v_w;  NT = 8;  N = 128; dstoff = OFF_V;  lf = f - 128; scale_g = true; }
    else if (f < 256) { src = o_w;  NT = 8;  N = 128; dstoff = OFF_O;  lf = f - 192; }
    else if (f < 512) { src = f1w;  NT = 32; N = 512; dstoff = OFF_F1; lf = f - 256; }
    else if (f < 768) { src = f2w;  NT = 8;  N = 128; dstoff = OFF_F2; lf = f - 512; }
    else if (f < 864) { src = o1w;             src2 = o1w + 256 * 384; sgn =  1.f;
                        NT = 24; N = 384; dstoff = OFF_XC; lf = f - 768; }
    else              { src = o1w + 128 * 384; src2 = o1w + 256 * 384; sgn = -1.f;
                        NT = 24; N = 384; dstoff = OFF_CC; lf = f - 864; }
    int kt = lf / NT, nt = lf - kt * NT;
    int row0 = kt * 32 + rq, col = nt * 16 + cq;
    s8v o;
#pragma unroll
    for (int j = 0; j < 8; ++j) {
        float v = src[(size_t)(row0 + j) * N + col];
        if (src2) v += sgn * src2[(size_t)(row0 + j) * N + col];
        if (scale_g) v *= ctx_g[row0 + j];
        o[j] = (short)f2bf(v);
    }
    *(s8v*)(ws + dstoff + (size_t)lf * 512 + (size_t)lane * 8) = o;
}

// ---------------- prologue 2 (guard-only, outputs unconsumed this round) ----------------
__global__ __launch_bounds__(64) void kv_kernel(const u16* __restrict__ nrmb,
                                                u16* __restrict__ ws)
{
    const int lane = threadIdx.x;
    const int cidx = lane & 15, quad = lane >> 4;
    const int dp0 = blockIdx.x * 16;
    __shared__ u16 vtile[16 * 136];
    s8v a[4];
#pragma unroll
    for (int kt = 0; kt < 4; ++kt)
        a[kt] = *(const s8v*)(nrmb + (size_t)(dp0 + cidx) * 128 + kt * 32 + 8 * quad);
#pragma unroll 1
    for (int ly = 0; ly < 2; ++ly) {
#pragma unroll 1
        for (int m = 0; m < 2; ++m) {
            const u16* W = ws + (m ? OFF_V : OFF_K) + ly * 16384;
            f4v acc[8];
#pragma unroll
            for (int nt = 0; nt < 8; ++nt) { f4v z = {0.f, 0.f, 0.f, 0.f}; acc[nt] = z; }
#pragma unroll
            for (int kt = 0; kt < 4; ++kt)
#pragma unroll
                for (int nt = 0; nt < 8; ++nt) {
                    s8v w = *(const s8v*)(W + ((size_t)((kt * 8 + nt) * 64 + lane)) * 8);
                    acc[nt] = __builtin_amdgcn_mfma_f32_16x16x32_bf16(a[kt], w, acc[nt], 0, 0, 0);
                }
            if (m == 0) {
                u16* K = ws + OFF_KB + (size_t)ly * NDP * 128;
#pragma unroll
                for (int nt = 0; nt < 8; ++nt)
#pragma unroll
                    for (int r = 0; r < 4; ++r)
                        K[(size_t)(dp0 + 4 * quad + r) * 128 + 16 * nt + cidx] = f2bf(acc[nt][r]);
            } else {
                asm volatile("s_waitcnt lgkmcnt(0)" ::: "memory");
#pragma unroll
                for (int nt = 0; nt < 8; ++nt)
#pragma unroll
                    for (int r = 0; r < 4; ++r)
                        vtile[(4 * quad + r) * 136 + 16 * nt + cidx] = f2bf(acc[nt][r]);
                asm volatile("s_waitcnt lgkmcnt(0)" ::: "memory");
                u16* Vt = ws + OFF_VT + (size_t)ly * 128 * NDP;
#pragma unroll
                for (int cc = 0; cc < 2; ++cc) {
                    int ch = lane + 64 * cc;
                    s8v tv0, tv1;
#pragma unroll
                    for (int d = 0; d < 8; ++d) tv0[d] = (short)vtile[d * 136 + ch];
#pragma unroll
                    for (int d = 0; d < 8; ++d) tv1[d] = (short)vtile[(8 + d) * 136 + ch];
                    *(s8v*)(Vt + (size_t)ch * NDP + dp0)     = tv0;
                    *(s8v*)(Vt + (size_t)ch * NDP + dp0 + 8) = tv1;
                }
            }
        }
    }
}

// ---------------- main fused kernel (exact R8 structure, known-good 303us) ----------------
__global__ __launch_bounds__(256, 2) void fused_base(
    const u16*  __restrict__ nrmb, const float* __restrict__ fmu,
    const u16*  __restrict__ wsb,
    const float* __restrict__ qb, const float* __restrict__ ob,
    const float* __restrict__ f1b, const float* __restrict__ f2b,
    const float* __restrict__ o1b, const float* __restrict__ o2w,
    const float* __restrict__ o2b,
    float* __restrict__ out)
{
    const int tid  = threadIdx.x;
    const int wid  = tid >> 6;
    const int lane = tid & 63;
    const int cidx = lane & 15, quad = lane >> 4;
    const int n0 = blockIdx.x * 64 + wid * 16;
    const int b  = n0 / (HU_ * WU_);
    const int rem = n0 - b * (HU_ * WU_);
    const int hu  = rem / WU_;
    const int wu0 = rem - hu * WU_;

    __shared__ __align__(16) u16 wlds[2][4096];
    __shared__ __align__(16) u16 arena2[4][2 * SLOT];
    u16*   const arena = arena2[wid];
    float* const s_at  = (float*)(arena + SLOT + 1024);
    float* const s_rs  = s_at;

    const float* vbp = (const float*)(wsb + OFF_VB);

    float xacc[8][4];
#pragma unroll
    for (int nt = 0; nt < 8; ++nt) {
        int ch = 16 * nt + cidx;
        float4 v = *(const float4*)(fmu + ((size_t)(b * C_ + ch) * HU_ + hu) * WU_ + wu0 + 4 * quad);
        xacc[nt][0] = v.x; xacc[nt][1] = v.y; xacc[nt][2] = v.z; xacc[nt][3] = v.w;
    }

    const float slopes[4] = {0.451801007f, 0.204124145f, 0.092223264f, 0.041666668f};
    const int ry0 = min(hu >> 1, HD_ - 1);
    const int ry1 = min((hu >> 1) + 1, HD_ - 1);
    const float dyv0 = -(float)abs(hu - 2 * ry0);
    const float dyv1 = -(float)abs(hu - 2 * ry1);

    const int k2l = cidx & 3;
    const int ryl = (k2l >> 1) ? ry1 : ry0;
    int cbase[4];
#pragma unroll
    for (int mt = 0; mt < 4; ++mt) {
        int p = 4 * mt + (cidx >> 2);
        int rxv = min(((wu0 + p) >> 1) + (k2l & 1), WD_ - 1);
        cbase[mt] = ((b * HD_ + ryl) * WD_ + rxv) * 128;
    }

#pragma unroll 1
    for (int ly = 0; ly < 2; ++ly) {
        const u16* Wq = wsb + OFF_Q  + ly * 16384;
        const u16* Wk = wsb + OFF_K  + ly * 16384;
        const u16* Wv = wsb + OFF_V  + ly * 16384;
        const u16* Wo = wsb + OFF_O  + ly * 16384;
        const u16* W1 = wsb + OFF_F1 + ly * 65536;
        const u16* W2 = wsb + OFF_F2 + ly * 65536;

        s8v fr[4][2];

#pragma unroll
        for (int jl = 0; jl < 2; ++jl) {
            int j = 2 * wid + jl;
            glds1(Wq + (size_t)j * 512, &wlds[0][j * 512], lane);
        }
#pragma unroll
        for (int jl = 0; jl < 2; ++jl) {
            int j = 2 * wid + jl;
            glds1(Wq + (size_t)(8 + j) * 512, &wlds[1][j * 512], lane);
        }

        // ---- xn = LN(x,1e-6) -> slot0 ----
        {
            float mo[4], io[4];
#pragma unroll
            for (int r = 0; r < 4; ++r) {
                float s = 0.f, ss = 0.f;
#pragma unroll
                for (int nt = 0; nt < 8; ++nt) { float v = xacc[nt][r]; s += v; ss += v * v; }
#pragma unroll
                for (int m = 1; m <= 8; m <<= 1) { s += __shfl_xor(s, m, 64); ss += __shfl_xor(ss, m, 64); }
                float mn = s * (1.f / 128.f);
                mo[r] = mn; io[r] = rsqrtf(ss * (1.f / 128.f) - mn * mn + 1e-6f);
            }
#pragma unroll
            for (int nt = 0; nt < 8; ++nt)
#pragma unroll
                for (int r = 0; r < 4; r += 2)
                    st2bf(arena + (4 * quad + r) * 136 + 16 * nt + cidx,
                          arena + (4 * quad + r + 1) * 136 + 16 * nt + cidx,
                          (xacc[nt][r] - mo[r]) * io[r],
                          (xacc[nt][r + 1] - mo[r + 1]) * io[r + 1]);
        }
        WFENCE();
        s8v a_xn[4];
#pragma unroll
        for (int kt = 0; kt < 4; ++kt)
            a_xn[kt] = *(const s8v*)(arena + cidx * 136 + kt * 32 + 8 * quad);

        // ---- q GEMM (streamed; group g = kt) ----
        {
            f4v qa[8];
#pragma unroll
            for (int nt = 0; nt < 8; ++nt) {
                float bvv = qb[ly * C_ + 16 * nt + cidx];
                f4v t = {bvv, bvv, bvv, bvv}; qa[nt] = t;
            }
#pragma unroll
            for (int g = 0; g < 4; ++g) {
                if (g < 3) { GW2(); } else { GW0(); }
#pragma unroll
                for (int nt = 0; nt < 8; ++nt) {
                    s8v w = *(const s8v*)&wlds[g & 1][nt * 512 + lane * 8];
                    qa[nt] = __builtin_amdgcn_mfma_f32_16x16x32_bf16(a_xn[g], w, qa[nt], 0, 0, 0);
                }
                BAR();
                if (g < 2) {
#pragma unroll
                    for (int jl = 0; jl < 2; ++jl) {
                        int j = 2 * wid + jl;
                        glds1(Wq + (size_t)((g + 2) * 8 + j) * 512, &wlds[g & 1][j * 512], lane);
                    }
                }
            }
#pragma unroll
            for (int kt = 0; kt < 4; ++kt)
#pragma unroll
                for (int i = 0; i < 2; ++i)
                    fr[kt][i] = *(const s8v*)(nrmb + cbase[i] + kt * 32 + 8 * quad);
#pragma unroll
            for (int jl = 0; jl < 2; ++jl) {
                int j = 2 * wid + jl;
                glds1(Wk + (size_t)(((j & 3) * 8) + (j >> 2)) * 512, &wlds[0][j * 512], lane);
            }
#pragma unroll
            for (int jl = 0; jl < 2; ++jl) {
                int j = 2 * wid + jl;
                int jc = 8 + j;
                glds1(Wk + (size_t)(((jc & 3) * 8) + (jc >> 2)) * 512, &wlds[1][j * 512], lane);
            }
#pragma unroll
            for (int nt = 0; nt < 8; ++nt)
#pragma unroll
                for (int r = 0; r < 4; r += 2)
                    st2bf(arena + (4 * quad + r) * 136 + 16 * nt + cidx,
                          arena + (4 * quad + r + 1) * 136 + 16 * nt + cidx,
                          qa[nt][r], qa[nt][r + 1]);
        }
        WFENCE();

        // ---- k GEMM + fused raw scores (streamed; mh=g>>2, h=g&3) ----
#pragma unroll
        for (int g = 0; g < 8; ++g) {
            if (g < 7) { GW2(); } else { GW0(); }
            const int mh = g >> 2, h = g & 3;
            float part[2][4];
#pragma unroll
            for (int i = 0; i < 2; ++i)
#pragma unroll
                for (int r = 0; r < 4; ++r) part[i][r] = 0.f;
#pragma unroll
            for (int ntp = 0; ntp < 2; ++ntp) {
                const int nt = 2 * h + ntp;
                f4v ka[2];
#pragma unroll
                for (int i = 0; i < 2; ++i) { f4v t = {0.f, 0.f, 0.f, 0.f}; ka[i] = t; }
#pragma unroll
                for (int kt = 0; kt < 4; ++kt) {
                    s8v w = *(const s8v*)&wlds[g & 1][(ntp * 4 + kt) * 512 + lane * 8];
                    ka[0] = __builtin_amdgcn_mfma_f32_16x16x32_bf16(fr[kt][0], w, ka[0], 0, 0, 0);
                    ka[1] = __builtin_amdgcn_mfma_f32_16x16x32_bf16(fr[kt][1], w, ka[1], 0, 0, 0);
                }
#pragma unroll
                for (int i = 0; i < 2; ++i) {
                    float qv = bfu(arena[(4 * (2 * mh + i) + quad) * 136 + 16 * nt + cidx]);
#pragma unroll
                    for (int r = 0; r < 4; ++r) part[i][r] = fmaf(qv, ka[i][r], part[i][r]);
                }
            }
#pragma unroll
            for (int i = 0; i < 2; ++i)
#pragma unroll
                for (int r = 0; r < 4; ++r) {
#pragma unroll
                    for (int m = 1; m <= 8; m <<= 1) part[i][r] += __shfl_xor(part[i][r], m, 64);
                }
            if (cidx == 0) {
#pragma unroll
                for (int i = 0; i < 2; ++i) {
                    float4 t = {part[i][0], part[i][1], part[i][2], part[i][3]};
                    *(float4*)&s_at[(4 * (2 * mh + i) + quad) * 16 + 4 * h] = t;
                }
            }
            BAR();
            if (g == 2) {
#pragma unroll
                for (int kt = 0; kt < 4; ++kt)
#pragma unroll
                    for (int i = 0; i < 2; ++i)
                        fr[kt][i] = *(const s8v*)(nrmb + cbase[2 + i] + kt * 32 + 8 * quad);
            }
            if (g < 6) {
                const int gn = g + 2;
#pragma unroll
                for (int jl = 0; jl < 2; ++jl) {
                    int j = 2 * wid + jl;
                    int jc = 8 * (gn & 3) + j;
                    glds1(Wk + (size_t)(((jc & 3) * 8) + (jc >> 2)) * 512, &wlds[g & 1][j * 512], lane);
                }
            }
        }
#pragma unroll
        for (int kt = 0; kt < 4; ++kt)
#pragma unroll
            for (int i = 0; i < 2; ++i)
                fr[kt][i] = *(const s8v*)(nrmb + cbase[i] + kt * 32 + 8 * quad);
#pragma unroll
        for (int jl = 0; jl < 2; ++jl) {
            int j = 2 * wid + jl;
            glds1(Wv + (size_t)(((j & 3) * 8) + (j >> 2)) * 512, &wlds[0][j * 512], lane);
        }
#pragma unroll
        for (int jl = 0; jl < 2; ++jl) {
            int j = 2 * wid + jl;
            glds1(Wv + (size_t)(((j & 3) * 8) + 2 + (j >> 2)) * 512, &wlds[1][j * 512], lane);
        }
        WFENCE();

        // ---- softmax in place (wave-private s_at) ----
        {
            int p = lane >> 2, h = lane & 3;
            float4 sc = *(float4*)&s_at[p * 16 + 4 * h];
            int pw = wu0 + p;
            float sim[4] = {sc.x, sc.y, sc.z, sc.w};
#pragma unroll
            for (int r = 0; r < 4; ++r) {
                int rxv = min((pw >> 1) + (r & 1), WD_ - 1);
                float cd = ((r >> 1) ? dyv1 : dyv0) - (float)abs(pw - 2 * rxv);
                sim[r] = sim[r] * 0.17677669529663687f + slopes[h] * cd;
            }
            float mx = fmaxf(fmaxf(sim[0], sim[1]), fmaxf(sim[2], sim[3]));
            float e0 = __expf(sim[0] - mx), e1 = __expf(sim[1] - mx);
            float e2 = __expf(sim[2] - mx), e3 = __expf(sim[3] - mx);
            float si = 1.f / (e0 + e1 + e2 + e3);
            float4 at = {e0 * si, e1 * si, e2 * si, e3 * si};
            *(float4*)&s_at[p * 16 + 4 * h] = at;
        }
        WFENCE();

        // ---- v GEMM + fused o = attn@v -> oT slot0 (streamed, paired writes) ----
#pragma unroll
        for (int g = 0; g < 8; ++g) {
            if (g < 7) { GW2(); } else { GW0(); }
            const int mh = g >> 2, gp = g & 3;
            float4 at0 = *(float4*)&s_at[(4 * (2 * mh + 0) + quad) * 16 + 4 * gp];
            float4 at1 = *(float4*)&s_at[(4 * (2 * mh + 1) + quad) * 16 + 4 * gp];
            float ov[2][2];
#pragma unroll
            for (int ntp = 0; ntp < 2; ++ntp) {
                const int nt = 2 * gp + ntp;
                float vbb = vbp[ly * C_ + 16 * nt + cidx];
                f4v va[2];
#pragma unroll
                for (int i = 0; i < 2; ++i) { f4v t = {vbb, vbb, vbb, vbb}; va[i] = t; }
#pragma unroll
                for (int kt = 0; kt < 4; ++kt) {
                    s8v w = *(const s8v*)&wlds[g & 1][(ntp * 4 + kt) * 512 + lane * 8];
                    va[0] = __builtin_amdgcn_mfma_f32_16x16x32_bf16(fr[kt][0], w, va[0], 0, 0, 0);
                    va[1] = __builtin_amdgcn_mfma_f32_16x16x32_bf16(fr[kt][1], w, va[1], 0, 0, 0);
                }
                ov[ntp][0] = at0.x * va[0][0] + at0.y * va[0][1] + at0.z * va[0][2] + at0.w * va[0][3];
                ov[ntp][1] = at1.x * va[1][0] + at1.y * va[1][1] + at1.z * va[1][2] + at1.w * va[1][3];
            }
#pragma unroll
            for (int i = 0; i < 2; ++i) {
                const int mt = 2 * mh + i;
                st2bf(arena + (4 * mt + quad) * 136 + 16 * (2 * gp) + cidx,
                      arena + (4 * mt + quad) * 136 + 16 * (2 * gp + 1) + cidx,
                      ov[0][i], ov[1][i]);
            }
            BAR();
            if (g == 2) {
#pragma unroll
                for (int kt = 0; kt < 4; ++kt)
#pragma unroll
                    for (int i = 0; i < 2; ++i)
                        fr[kt][i] = *(const s8v*)(nrmb + cbase[2 + i] + kt * 32 + 8 * quad);
            }
            if (g < 6) {
                const int gq = (g + 2) & 3;
#pragma unroll
                for (int jl = 0; jl < 2; ++jl) {
                    int j = 2 * wid + jl;
                    glds1(Wv + (size_t)(((j & 3) * 8) + 2 * gq + (j >> 2)) * 512, &wlds[g & 1][j * 512], lane);
                }
            }
        }
#pragma unroll
        for (int jl = 0; jl < 2; ++jl) {
            int j = 2 * wid + jl;
            glds1(Wo + (size_t)j * 512, &wlds[0][j * 512], lane);
        }
#pragma unroll
        for (int jl = 0; jl < 2; ++jl) {
            int j = 2 * wid + jl;
            glds1(Wo + (size_t)(8 + j) * 512, &wlds[1][j * 512], lane);
        }
        WFENCE();

        // ---- x += o @ Wo + ob (streamed) ----
        {
            s8v a_o[4];
#pragma unroll
            for (int kt = 0; kt < 4; ++kt)
                a_o[kt] = *(const s8v*)(arena + cidx * 136 + kt * 32 + 8 * quad);
            f4v oa[8];
#pragma unroll
            for (int nt = 0; nt < 8; ++nt) {
                float bvv = ob[ly * C_ + 16 * nt + cidx];
                f4v t = {bvv, bvv, bvv, bvv}; oa[nt] = t;
            }
#pragma unroll
            for (int g = 0; g < 4; ++g) {
                if (g < 3) { GW2(); } else { GW0(); }
#pragma unroll
                for (int nt = 0; nt < 8; ++nt) {
                    s8v w = *(const s8v*)&wlds[g & 1][nt * 512 + lane * 8];
                    oa[nt] = __builtin_amdgcn_mfma_f32_16x16x32_bf16(a_o[g], w, oa[nt], 0, 0, 0);
                }
                BAR();
                if (g < 2) {
#pragma unroll
                    for (int jl = 0; jl < 2; ++jl) {
                        int j = 2 * wid + jl;
                        glds1(Wo + (size_t)((g + 2) * 8 + j) * 512, &wlds[g & 1][j * 512], lane);
                    }
                }
            }
#pragma unroll
            for (int jl = 0; jl < 2; ++jl) {
                int j = 2 * wid + jl;
                glds1(W1 + (size_t)j * 512, &wlds[0][j * 512], lane);
            }
#pragma unroll
            for (int jl = 0; jl < 2; ++jl) {
                int j = 2 * wid + jl;
                glds1(W1 + (size_t)(32 + j) * 512, &wlds[1][j * 512], lane);
            }
#pragma unroll
            for (int nt = 0; nt < 8; ++nt)
#pragma unroll
                for (int r = 0; r < 4; ++r) xacc[nt][r] += oa[nt][r];
        }

        // ---- hn = LN(x,1e-6) -> slot0 ----
        {
            float mo[4], io[4];
#pragma unroll
            for (int r = 0; r < 4; ++r) {
                float s = 0.f, ss = 0.f;
#pragma unroll
                for (int nt = 0; nt < 8; ++nt) { float v = xacc[nt][r]; s += v; ss += v * v; }
#pragma unroll
                for (int m = 1; m <= 8; m <<= 1) { s += __shfl_xor(s, m, 64); ss += __shfl_xor(ss, m, 64); }
                float mn = s * (1.f / 128.f);
                mo[r] = mn; io[r] = rsqrtf(ss * (1.f / 128.f) - mn * mn + 1e-6f);
            }
#pragma unroll
            for (int nt = 0; nt < 8; ++nt)
#pragma unroll
                for (int r = 0; r < 4; r += 2)
                    st2bf(arena + (4 * quad + r) * 136 + 16 * nt + cidx,
                          arena + (4 * quad + r + 1) * 136 + 16 * nt + cidx,
                          (xacc[nt][r] - mo[r]) * io[r],
                          (xacc[nt][r + 1] - mo[r + 1]) * io[r + 1]);
        }
        WFENCE();
        s8v a_hn[4];
#pragma unroll
        for (int kt = 0; kt < 4; ++kt)
            a_hn[kt] = *(const s8v*)(arena + cidx * 136 + kt * 32 + 8 * quad);

        // ---- ffn: 4 chunks of 128 cols, both GEMMs streamed ----
        {
            f4v ga[8];
#pragma unroll
            for (int nt = 0; nt < 8; ++nt) {
                float bvv = f2b[ly * C_ + 16 * nt + cidx];
                f4v t = {bvv, bvv, bvv, bvv}; ga[nt] = t;
            }
#pragma unroll 1
            for (int c = 0; c < 4; ++c) {
                f4v fa[8];
#pragma unroll
                for (int nt = 0; nt < 8; ++nt) {
                    float bvv = f1b[ly * 512 + 128 * c + 16 * nt + cidx];
                    f4v t = {bvv, bvv, bvv, bvv}; fa[nt] = t;
                }
#pragma unroll
                for (int g = 0; g < 4; ++g) {
                    if (g < 3) { GW2(); } else { GW0(); }
#pragma unroll
                    for (int nt = 0; nt < 8; ++nt) {
                        s8v w = *(const s8v*)&wlds[g & 1][nt * 512 + lane * 8];
                        fa[nt] = __builtin_amdgcn_mfma_f32_16x16x32_bf16(a_hn[g], w, fa[nt], 0, 0, 0);
                    }
                    BAR();
                    if (g < 2) {
#pragma unroll
                        for (int jl = 0; jl < 2; ++jl) {
                            int j = 2 * wid + jl;
                            glds1(W1 + (size_t)((g + 2) * 32 + 8 * c + j) * 512, &wlds[g & 1][j * 512], lane);
                        }
                    }
                }
#pragma unroll
                for (int jl = 0; jl < 2; ++jl) {
                    int j = 2 * wid + jl;
                    glds1(W2 + (size_t)(32 * c + j) * 512, &wlds[0][j * 512], lane);
                }
#pragma unroll
                for (int jl = 0; jl < 2; ++jl) {
                    int j = 2 * wid + jl;
                    glds1(W2 + (size_t)(32 * c + 8 + j) * 512, &wlds[1][j * 512], lane);
                }
#pragma unroll
                for (int nt = 0; nt < 8; ++nt)
#pragma unroll
                    for (int r = 0; r < 4; r += 2)
                        st2bf(arena + SLOT + (4 * quad + r) * 136 + 16 * nt + cidx,
                              arena + SLOT + (4 * quad + r + 1) * 136 + 16 * nt + cidx,
                              gelu_tanh(fa[nt][r]), gelu_tanh(fa[nt][r + 1]));
                WFENCE();
#pragma unroll
                for (int g = 0; g < 4; ++g) {
                    if (g < 3) { GW2(); } else { GW0(); }
                    s8v aa = *(const s8v*)(arena + SLOT + cidx * 136 + g * 32 + 8 * quad);
#pragma unroll
                    for (int nt = 0; nt < 8; ++nt) {
                        s8v w = *(const s8v*)&wlds[g & 1][nt * 512 + lane * 8];
                        ga[nt] = __builtin_amdgcn_mfma_f32_16x16x32_bf16(aa, w, ga[nt], 0, 0, 0);
                    }
                    BAR();
                    if (g < 2) {
#pragma unroll
                        for (int jl = 0; jl < 2; ++jl) {
                            int j = 2 * wid + jl;
                            glds1(W2 + (size_t)(32 * c + (g + 2) * 8 + j) * 512, &wlds[g & 1][j * 512], lane);
                        }
                    }
                }
                if (c < 3) {
#pragma unroll
                    for (int jl = 0; jl < 2; ++jl) {
                        int j = 2 * wid + jl;
                        glds1(W1 + (size_t)(8 * (c + 1) + j) * 512, &wlds[0][j * 512], lane);
                    }
#pragma unroll
                    for (int jl = 0; jl < 2; ++jl) {
                        int j = 2 * wid + jl;
                        glds1(W1 + (size_t)(32 + 8 * (c + 1) + j) * 512, &wlds[1][j * 512], lane);
                    }
                }
            }
#pragma unroll
            for (int nt = 0; nt < 8; ++nt)
#pragma unroll
                for (int r = 0; r < 4; ++r) xacc[nt][r] += ga[nt][r];
        }
    } // layer loop

    // ================= head =================
    const u16* Wxc = wsb + OFF_XC;
    const u16* Wcc = wsb + OFF_CC;
#pragma unroll
    for (int jl = 0; jl < 3; ++jl) {
        int j = 3 * wid + jl;
        glds1(Wxc + (size_t)((j / 3) * 24 + (j % 3)) * 512, &wlds[j / 6][(j % 6) * 512], lane);
    }
    {
        float mo[4], io[4];
#pragma unroll
        for (int r = 0; r < 4; ++r) {
            float s = 0.f, ss = 0.f;
#pragma unroll
            for (int nt = 0; nt < 8; ++nt) { float v = xacc[nt][r]; s += v; ss += v * v; }
#pragma unroll
            for (int m = 1; m <= 8; m <<= 1) { s += __shfl_xor(s, m, 64); ss += __shfl_xor(ss, m, 64); }
            float mn = s * (1.f / 128.f);
            mo[r] = mn; io[r] = rsqrtf(ss * (1.f / 128.f) - mn * mn + 1e-6f);
        }
#pragma unroll
        for (int nt = 0; nt < 8; ++nt)
#pragma unroll
            for (int r = 0; r < 4; r += 2)
                st2bf(arena + (4 * quad + r) * 136 + 16 * nt + cidx,
                      arena + (4 * quad + r + 1) * 136 + 16 * nt + cidx,
                      (xacc[nt][r] - mo[r]) * io[r],
                      (xacc[nt][r + 1] - mo[r + 1]) * io[r + 1]);
    }
    WFENCE();
    s8v a_xf[4];
#pragma unroll
    for (int kt = 0; kt < 4; ++kt)
        a_xf[kt] = *(const s8v*)(arena + cidx * 136 + kt * 32 + 8 * quad);

    float part[4][4];
#pragma unroll
    for (int mt = 0; mt < 4; ++mt)
#pragma unroll
        for (int r = 0; r < 4; ++r) part[mt][r] = 0.f;

#pragma unroll 1
    for (int it = 0; it < 8; ++it) {
        const int nbase = 6 * (it >> 1) + 3 * (it & 1);
        {
            f4v hx[3];
#pragma unroll
            for (int ntl = 0; ntl < 3; ++ntl) {
                float hb = o1b[16 * (nbase + ntl) + cidx];
                f4v t = {hb, hb, hb, hb}; hx[ntl] = t;
            }
            if (wid < 2) { asm volatile("s_waitcnt vmcnt(0)" ::: "memory"); }
            BAR();
#pragma unroll
            for (int kt = 0; kt < 2; ++kt)
#pragma unroll
                for (int ntl = 0; ntl < 3; ++ntl) {
                    s8v w = *(const s8v*)&wlds[0][(kt * 3 + ntl) * 512 + lane * 8];
                    hx[ntl] = __builtin_amdgcn_mfma_f32_16x16x32_bf16(a_xf[kt], w, hx[ntl], 0, 0, 0);
                }
            if (wid >= 2) { asm volatile("s_waitcnt vmcnt(0)" ::: "memory"); }
            BAR();
#pragma unroll
            for (int kt = 2; kt < 4; ++kt)
#pragma unroll
                for (int ntl = 0; ntl < 3; ++ntl) {
                    s8v w = *(const s8v*)&wlds[1][((kt - 2) * 3 + ntl) * 512 + lane * 8];
                    hx[ntl] = __builtin_amdgcn_mfma_f32_16x16x32_bf16(a_xf[kt], w, hx[ntl], 0, 0, 0);
                }
            BAR();
            if (it < 7) {
                const int nb2 = 6 * ((it + 1) >> 1) + 3 * ((it + 1) & 1);
#pragma unroll
                for (int jl = 0; jl < 3; ++jl) {
                    int j = 3 * wid + jl;
                    glds1(Wxc + (size_t)((j / 3) * 24 + nb2 + (j % 3)) * 512, &wlds[j / 6][(j % 6) * 512], lane);
                }
            }
#pragma unroll
            for (int ntl = 0; ntl < 3; ++ntl)
#pragma unroll
                for (int r = 0; r < 4; r += 2)
                    st2bf(arena + SLOT + (4 * quad + r) * 56 + 16 * ntl + cidx,
                          arena + SLOT + (4 * quad + r + 1) * 56 + 16 * ntl + cidx,
                          hx[ntl][r], hx[ntl][r + 1]);
        }
        WFENCE();

        f4v hc[3][4];
#pragma unroll
        for (int ntl = 0; ntl < 3; ++ntl)
#pragma unroll
            for (int mt = 0; mt < 4; ++mt) { f4v t = {0.f, 0.f, 0.f, 0.f}; hc[ntl][mt] = t; }
#pragma unroll 2
        for (int kt = 0; kt < 4; ++kt) {
            s8v frh[4];
#pragma unroll
            for (int mt = 0; mt < 4; ++mt)
                frh[mt] = *(const s8v*)(nrmb + cbase[mt] + kt * 32 + 8 * quad);
#pragma unroll
            for (int ntl = 0; ntl < 3; ++ntl) {
                s8v w = *(const s8v*)(Wcc + ((size_t)((kt * 24 + nbase + ntl) * 64 + lane)) * 8);
#pragma unroll
                for (int mt = 0; mt < 4; ++mt)
                    hc[ntl][mt] = __builtin_amdgcn_mfma_f32_16x16x32_bf16(frh[mt], w, hc[ntl][mt], 0, 0, 0);
            }
        }

#pragma unroll
        for (int ntl = 0; ntl < 3; ++ntl) {
            float w2v = o2w[16 * (nbase + ntl) + cidx];
#pragma unroll
            for (int mt = 0; mt < 4; ++mt)
#pragma unroll
                for (int r = 0; r < 4; ++r) {
                    float h1 = hc[ntl][mt][r] +
                               bfu(arena[SLOT + (4 * mt + quad) * 56 + 16 * ntl + cidx]);
                    part[mt][r] = fmaf(gelu_erf(h1), w2v, part[mt][r]);
                }
        }
        WFENCE();
    }

#pragma unroll
    for (int mt = 0; mt < 4; ++mt)
#pragma unroll
        for (int r = 0; r < 4; ++r) {
#pragma unroll
            for (int m = 1; m <= 8; m <<= 1) part[mt][r] += __shfl_xor(part[mt][r], m, 64);
            part[mt][r] += o2b[0];
        }
    if (cidx == 0) {
#pragma unroll
        for (int mt = 0; mt < 4; ++mt) {
            float4 t = {part[mt][0], part[mt][1], part[mt][2], part[mt][3]};
            *(float4*)&s_rs[(4 * mt + quad) * 4] = t;
        }
    }
    WFENCE();

    if (lane < 16) {
        int p = lane;
        float4 vv = *(float4*)&s_rs[4 * p];
        float mx = fmaxf(fmaxf(vv.x, vv.y), fmaxf(vv.z, vv.w));
        float e0 = __expf(vv.x - mx), e1 = __expf(vv.y - mx);
        float e2 = __expf(vv.z - mx), e3 = __expf(vv.w - mx);
        float si = 1.f / (e0 + e1 + e2 + e3);
        size_t base = ((size_t)(b * 4) * HU_ + hu) * WU_ + wu0 + p;
        out[base]                          = e0 * si;
        out[base + (size_t)HU_ * WU_]      = e1 * si;
        out[base + (size_t)2 * HU_ * WU_]  = e2 * si;
        out[base + (size_t)3 * HU_ * WU_]  = e3 * si;
    }
}

extern "C" void kernel_launch(void* const* d_in, const int* in_sizes, int n_in,
                              void* d_out, int out_size, void* d_ws, size_t ws_size,
                              hipStream_t stream) {
    const float* feat_map    = (const float*)d_in[0];
    const float* feat_map_up = (const float*)d_in[1];
    const float* ctx_ln_b    = (const float*)d_in[2];
    const float* q_w  = (const float*)d_in[3];
    const float* q_b  = (const float*)d_in[4];
    const float* k_w  = (const float*)d_in[5];
    const float* v_w  = (const float*)d_in[7];
    const float* v_b  = (const float*)d_in[8];
    const float* o_w  = (const float*)d_in[9];
    const float* o_b  = (const float*)d_in[10];
    const float* fc1_w = (const float*)d_in[11];
    const float* fc1_b = (const float*)d_in[12];
    const float* fc2_w = (const float*)d_in[13];
    const float* fc2_b = (const float*)d_in[14];
    const float* out1_w = (const float*)d_in[15];
    const float* out1_b = (const float*)d_in[16];
    const float* out2_w = (const float*)d_in[17];
    const float* out2_b = (const float*)d_in[18];
    const float* ctx_ln_g = (const float*)d_in[19];
    float* out = (float*)d_out;
    u16* ws = (u16*)d_ws;

    prologue_all<<<370, 256, 0, stream>>>(q_w, k_w, v_w, o_w, fc1_w, fc2_w, out1_w,
                                          ctx_ln_g, ctx_ln_b, v_b, feat_map, ws);

    // BISECT: kv_kernel runs (guard-protected) but nothing consumes Kb/Vt.
    // Pass => kv is side-effect-clean and the R9/R10 NaN lives in the
    // fused consumption path (next round: scores-only hybrid).
    // Fail => kv itself corrupts memory (ws smaller than guard believes).
    if (ws_size >= WS_NEED) {
        kv_kernel<<<NDP / 16, 64, 0, stream>>>(ws + OFF_NRM, ws);
    }

    fused_base<<<768, 256, 0, stream>>>(
        ws + OFF_NRM, feat_map_up, ws,
        q_b, o_b, fc1_b, fc2_b,
        out1_b, out2_w, out2_b, out);
}